// Round 5
// baseline (398.112 us; speedup 1.0000x reference)
//
#include <hip/hip_runtime.h>

// ---------------------------------------------------------------------------
// B=8, S=4096 (rows = 32768), D=1024, DS=64
// segments: qk 512 (tiles 0-31) | v 256 (32-47) | rel 128 (48-55) | val 64 (56-59)
// outputs (flat fp32): idx_qk 8x64 | idx_v 8x32 | rel_Q 8x128 | rel_K 8x128 | val_w 8x64
// R5: kill the 16-cacheline-per-instruction fragment loads. W and emb are
// pre-permuted into fragment-linear ("swizzled") buffers so every B-frag load
// is base + lane*16B (fully coalesced). k_main: block=64 rows; wave w computes
// M-tile w full-K (proj), h -> shared LDS fp32, then shared-A two-pass
// segment-softmax agg with waves striding nt. Split-bf16 3-term MFMA as R2-R4.
// ---------------------------------------------------------------------------

typedef short short8 __attribute__((ext_vector_type(8)));   // 8 bf16 = 4 VGPR
typedef float f32x4 __attribute__((ext_vector_type(4)));

__device__ __forceinline__ unsigned short f32_to_bf16(float f) {
  unsigned u = __float_as_uint(f);
  u += 0x7FFF + ((u >> 16) & 1);  // RNE
  return (unsigned short)(u >> 16);
}
__device__ __forceinline__ float bf16_to_f32(unsigned short h) {
  return __uint_as_float(((unsigned)h) << 16);
}
__device__ __forceinline__ void split8(const float4& a0, const float4& a1,
                                       short8& hi, short8& lo) {
  float af[8] = {a0.x, a0.y, a0.z, a0.w, a1.x, a1.y, a1.z, a1.w};
#pragma unroll
  for (int j = 0; j < 8; ++j) {
    unsigned short h = f32_to_bf16(af[j]);
    hi[j] = (short)h;
    lo[j] = (short)f32_to_bf16(af[j] - bf16_to_f32(h));
  }
}
#define MFMA(a, b, c) __builtin_amdgcn_mfma_f32_16x16x32_bf16(a, b, c, 0, 0, 0)

// ---- k_prep1: zero wg; rnorm[n] = 1/||emb_n|| ----
__global__ __launch_bounds__(256) void k_prep1(const float* __restrict__ emb,
                                               float* __restrict__ rnorm,
                                               float* __restrict__ wg) {
  int gid = blockIdx.x * 256 + threadIdx.x;
  for (int i = gid; i < 7680; i += gridDim.x * 256) wg[i] = 0.f;
  int wid = gid >> 6, lane = gid & 63;
  int nw = gridDim.x * 4;
  for (int n = wid; n < 960; n += nw) {
    float v = emb[n * 64 + lane];
    float s = v * v;
#pragma unroll
    for (int off = 1; off < 64; off <<= 1) s += __shfl_xor(s, off);
    if (lane == 0) rnorm[n] = 1.0f / sqrtf(s);
  }
}

// ---- k_prep2: build fragment-linear (swizzled) W and emb hi/lo buffers ----
// wswz: [nt(4)][ks(32)][lane(64)][8]  eswz: [nt(60)][ks(2)][lane(64)][8]
__global__ __launch_bounds__(256) void k_prep2(const float* __restrict__ pw,
                                               const float* __restrict__ emb,
                                               const float* __restrict__ rnorm,
                                               unsigned short* __restrict__ wshi,
                                               unsigned short* __restrict__ wslo,
                                               unsigned short* __restrict__ eshi,
                                               unsigned short* __restrict__ eslo) {
  int t = blockIdx.x * 256 + threadIdx.x;
  if (t < 8192) {  // W: t = (nt*32 + ks)*64 + lane
    int lane = t & 63, ks = (t >> 6) & 31, nt = t >> 11;
    int c = lane & 15, q = lane >> 4;
    const float* src = pw + (size_t)(nt * 16 + c) * 1024 + ks * 32 + q * 8;
#pragma unroll
    for (int j = 0; j < 8; ++j) {
      float v = src[j];
      unsigned short h = f32_to_bf16(v);
      wshi[(size_t)t * 8 + j] = h;
      wslo[(size_t)t * 8 + j] = f32_to_bf16(v - bf16_to_f32(h));
    }
  } else if (t < 8192 + 7680) {  // emb: u = (nt*2 + ks)*64 + lane
    int u = t - 8192;
    int lane = u & 63, ks = (u >> 6) & 1, nt = u >> 7;
    int c = lane & 15, q = lane >> 4;
    int n = nt * 16 + c;
    float rn = rnorm[n];
    const float* src = emb + (size_t)n * 64 + ks * 32 + q * 8;
#pragma unroll
    for (int j = 0; j < 8; ++j) {
      float v = src[j] * rn;
      unsigned short h = f32_to_bf16(v);
      eshi[(size_t)u * 8 + j] = h;
      eslo[(size_t)u * 8 + j] = f32_to_bf16(v - bf16_to_f32(h));
    }
  }
}

// ---- k_main: fused proj + two-pass segment-softmax agg, 64 rows/block ----
__global__ __launch_bounds__(256) void k_main(const float* __restrict__ x,
                                              const unsigned short* __restrict__ wshi,
                                              const unsigned short* __restrict__ wslo,
                                              const float* __restrict__ pb,
                                              const unsigned short* __restrict__ eshi,
                                              const unsigned short* __restrict__ eslo,
                                              const float* __restrict__ imp,
                                              float* __restrict__ wg) {
  __shared__ __align__(16) float hsf[64][68];  // h fp32, padded
  __shared__ float zpart[4][64][4];            // [wave][row][seg]
  __shared__ float coefL[64][4];               // imp/Z

  int tid = threadIdx.x, w = tid >> 6, lane = tid & 63;
  int q = lane >> 4, c = lane & 15;
  int row0 = blockIdx.x * 64;
  int b = row0 >> 12;

  // ========== proj: wave w computes h rows [row0+16w, row0+16w+16), full K ==========
  f32x4 acc[4];
#pragma unroll
  for (int nt = 0; nt < 4; ++nt) acc[nt] = (f32x4){0.f, 0.f, 0.f, 0.f};

  const float* ap = x + (size_t)(row0 + w * 16 + c) * 1024 + q * 8;
#pragma unroll 8
  for (int ks = 0; ks < 32; ++ks) {
    float4 ca = *(const float4*)(ap + ks * 32);
    float4 cb = *(const float4*)(ap + ks * 32 + 4);
    short8 ahi, alo;
    split8(ca, cb, ahi, alo);
#pragma unroll
    for (int nt = 0; nt < 4; ++nt) {
      size_t fo = ((size_t)(nt * 32 + ks) * 64 + lane) * 8;  // coalesced: lane*16B
      short8 bhi = *(const short8*)(wshi + fo);
      short8 blo = *(const short8*)(wslo + fo);
      acc[nt] = MFMA(ahi, bhi, acc[nt]);
      acc[nt] = MFMA(ahi, blo, acc[nt]);
      acc[nt] = MFMA(alo, bhi, acc[nt]);
    }
  }
#pragma unroll
  for (int nt = 0; nt < 4; ++nt)
#pragma unroll
    for (int r = 0; r < 4; ++r)
      hsf[w * 16 + q * 4 + r][nt * 16 + c] = acc[nt][r] + pb[nt * 16 + c];
  __syncthreads();

  // ========== A-frags for all 4 M-tiles from LDS ==========
  short8 Ahi[4][2], Alo[4][2];
#pragma unroll
  for (int mt = 0; mt < 4; ++mt)
#pragma unroll
    for (int ks = 0; ks < 2; ++ks) {
      float4 h0 = *(const float4*)&hsf[mt * 16 + c][ks * 32 + q * 8];
      float4 h1 = *(const float4*)&hsf[mt * 16 + c][ks * 32 + q * 8 + 4];
      split8(h0, h1, Ahi[mt][ks], Alo[mt][ks]);
    }

  // ========== pass 1: segment Z (wave strides nt = w + 4i) ==========
  f32x4 zacc[4];
#pragma unroll
  for (int mt = 0; mt < 4; ++mt) zacc[mt] = (f32x4){0.f, 0.f, 0.f, 0.f};
  int cur_seg = 0;
#pragma unroll
  for (int i = 0; i < 15; ++i) {
    int nt = w + 4 * i;
    int s = (nt < 32) ? 0 : (nt < 48) ? 1 : (nt < 56) ? 2 : 3;
    if (s != cur_seg) {
#pragma unroll
      for (int mt = 0; mt < 4; ++mt)
#pragma unroll
        for (int r = 0; r < 4; ++r) {
          float v = zacc[mt][r];
          v += __shfl_xor(v, 1); v += __shfl_xor(v, 2);
          v += __shfl_xor(v, 4); v += __shfl_xor(v, 8);
          if (c == 0) zpart[w][mt * 16 + q * 4 + r][cur_seg] = v;
          zacc[mt][r] = 0.f;
        }
      cur_seg = s;
    }
    size_t e0 = ((size_t)(nt * 2 + 0) * 64 + lane) * 8;  // coalesced
    size_t e1 = ((size_t)(nt * 2 + 1) * 64 + lane) * 8;
    short8 bhi0 = *(const short8*)(eshi + e0), bhi1 = *(const short8*)(eshi + e1);
    short8 blo0 = *(const short8*)(eslo + e0), blo1 = *(const short8*)(eslo + e1);
#pragma unroll
    for (int mt = 0; mt < 4; ++mt) {
      f32x4 l = (f32x4){0.f, 0.f, 0.f, 0.f};
      l = MFMA(Ahi[mt][0], bhi0, l); l = MFMA(Ahi[mt][1], bhi1, l);
      l = MFMA(Ahi[mt][0], blo0, l); l = MFMA(Ahi[mt][1], blo1, l);
      l = MFMA(Alo[mt][0], bhi0, l); l = MFMA(Alo[mt][1], bhi1, l);
#pragma unroll
      for (int r = 0; r < 4; ++r) zacc[mt][r] += __expf(l[r]);
    }
  }
#pragma unroll
  for (int mt = 0; mt < 4; ++mt)  // final flush (val segment)
#pragma unroll
    for (int r = 0; r < 4; ++r) {
      float v = zacc[mt][r];
      v += __shfl_xor(v, 1); v += __shfl_xor(v, 2);
      v += __shfl_xor(v, 4); v += __shfl_xor(v, 8);
      if (c == 0) zpart[w][mt * 16 + q * 4 + r][cur_seg] = v;
    }
  __syncthreads();
  {  // combine across waves: 256 threads = 64 rows x 4 segs
    int row = tid & 63, sg = tid >> 6;
    float Z = zpart[0][row][sg] + zpart[1][row][sg] + zpart[2][row][sg] + zpart[3][row][sg];
    coefL[row][sg] = imp[row0 + row] / Z;
  }
  __syncthreads();

  // ========== pass 2: weighted exp accumulation -> wg atomics ==========
  float cf[4][4];
  int cs2 = -1;
#pragma unroll
  for (int i = 0; i < 15; ++i) {
    int nt = w + 4 * i;
    int s = (nt < 32) ? 0 : (nt < 48) ? 1 : (nt < 56) ? 2 : 3;
    if (s != cs2) {
#pragma unroll
      for (int mt = 0; mt < 4; ++mt)
#pragma unroll
        for (int r = 0; r < 4; ++r) cf[mt][r] = coefL[mt * 16 + q * 4 + r][s];
      cs2 = s;
    }
    size_t e0 = ((size_t)(nt * 2 + 0) * 64 + lane) * 8;
    size_t e1 = ((size_t)(nt * 2 + 1) * 64 + lane) * 8;
    short8 bhi0 = *(const short8*)(eshi + e0), bhi1 = *(const short8*)(eshi + e1);
    short8 blo0 = *(const short8*)(eslo + e0), blo1 = *(const short8*)(eslo + e1);
    float wsum = 0.f;
#pragma unroll
    for (int mt = 0; mt < 4; ++mt) {
      f32x4 l = (f32x4){0.f, 0.f, 0.f, 0.f};
      l = MFMA(Ahi[mt][0], bhi0, l); l = MFMA(Ahi[mt][1], bhi1, l);
      l = MFMA(Ahi[mt][0], blo0, l); l = MFMA(Ahi[mt][1], blo1, l);
      l = MFMA(Alo[mt][0], bhi0, l); l = MFMA(Alo[mt][1], bhi1, l);
#pragma unroll
      for (int r = 0; r < 4; ++r) wsum = fmaf(__expf(l[r]), cf[mt][r], wsum);
    }
    wsum += __shfl_xor(wsum, 16);
    wsum += __shfl_xor(wsum, 32);  // sum over q -> all 64 rows of the block
    if (lane < 16) atomicAdd(&wg[b * 960 + nt * 16 + c], wsum);
  }
}

// ---- k_topk: parallel rank-based selection + ballot emission ----
__global__ __launch_bounds__(256) void k_topk(const float* __restrict__ wg,
                                              float* __restrict__ out) {
  __shared__ float vals[512];
  __shared__ int flags[512];
  int blk = blockIdx.x;
  int b = blk >> 2, t = blk & 3;
  int tid = threadIdx.x;
  const int Ns[4] = {512, 256, 128, 64};
  const int Ks[4] = {64, 32, 16, 3};
  const int Off[4] = {0, 512, 768, 896};
  int N = Ns[t], K = Ks[t], off = Off[t];
  for (int n = tid; n < N; n += 256) vals[n] = wg[b * 960 + off + n];
  __syncthreads();
  for (int n = tid; n < N; n += 256) {
    float v = vals[n];
    int rank = 0;
    for (int m = 0; m < N; ++m) {
      float u = vals[m];
      rank += (u > v || (u == v && m < n)) ? 1 : 0;
    }
    flags[n] = (rank < K) ? 1 : 0;
  }
  __syncthreads();
  if (t <= 1) {  // sorted ascending index emission via ballot prefix (wave 0)
    if (tid < 64) {
      int base = 0;
      for (int ch = 0; ch < N; ch += 64) {
        int n = ch + tid;
        int f = flags[n];
        unsigned long long mask = __ballot(f);
        if (f) {
          int pos = base + __popcll(mask & ((1ull << tid) - 1ull));
          if (t == 0) out[b * 64 + pos] = (float)n;
          else out[512 + b * 32 + pos] = (float)n;
        }
        base += __popcll(mask);
      }
    }
  } else if (t == 2) {
    for (int n = tid; n < 128; n += 256) {
      float v = flags[n] ? vals[n] : 0.f;
      out[768 + b * 128 + n] = v;
      out[1792 + b * 128 + n] = v;
    }
  } else {
    for (int n = tid; n < 64; n += 256) {
      float v = flags[n] ? vals[n] : 0.f;
      out[2816 + b * 64 + n] = v;
    }
  }
}

extern "C" void kernel_launch(void* const* d_in, const int* in_sizes, int n_in,
                              void* d_out, int out_size, void* d_ws, size_t ws_size,
                              hipStream_t stream) {
  const float* x   = (const float*)d_in[0];   // 8*4096*1024
  const float* imp = (const float*)d_in[1];   // 8*4096
  const float* pw  = (const float*)d_in[2];   // 64*1024
  const float* pb  = (const float*)d_in[3];   // 64
  const float* emb = (const float*)d_in[4];   // 1216*64
  float* out = (float*)d_out;                 // 3328 floats

  char* ws = (char*)d_ws;
  unsigned short* wshi = (unsigned short*)(ws);            // 128 KiB
  unsigned short* wslo = (unsigned short*)(ws + 131072);   // 128 KiB
  unsigned short* eshi = (unsigned short*)(ws + 262144);   // 120 KiB
  unsigned short* eslo = (unsigned short*)(ws + 385024);   // 120 KiB
  float*          rnrm = (float*)(ws + 507904);            // 3.75 KiB
  float*          wg   = (float*)(ws + 511744);            // 30 KiB

  hipLaunchKernelGGL(k_prep1, dim3(16), dim3(256), 0, stream, emb, rnrm, wg);
  hipLaunchKernelGGL(k_prep2, dim3(62), dim3(256), 0, stream, pw, emb, rnrm,
                     wshi, wslo, eshi, eslo);
  hipLaunchKernelGGL(k_main, dim3(512), dim3(256), 0, stream, x, wshi, wslo, pb,
                     eshi, eslo, imp, wg);
  hipLaunchKernelGGL(k_topk, dim3(32), dim3(256), 0, stream, wg, out);
}